// Round 4
// baseline (383.040 us; speedup 1.0000x reference)
//
#include <hip/hip_runtime.h>

typedef __bf16 bf16x8 __attribute__((ext_vector_type(8)));
typedef float f32x4 __attribute__((ext_vector_type(4)));

static __device__ __forceinline__ ushort f2b(float f) {
    uint32_t x = __float_as_uint(f);
    x += 0x7fffu + ((x >> 16) & 1u);   // RNE (finite values)
    return (ushort)(x >> 16);
}
static __device__ __forceinline__ float b2f(ushort u) {
    return __uint_as_float(((uint32_t)u) << 16);
}

typedef const __attribute__((address_space(1))) uint32_t gu32;
typedef __attribute__((address_space(3))) uint32_t lu32;
static __device__ __forceinline__ void gl_lds16(const void* g, void* l) {
    // async global->LDS, 16 B per lane; LDS dest = wave-uniform base + lane*16
    __builtin_amdgcn_global_load_lds((gu32*)g, (lu32*)l, 16, 0, 0);
}

// ---------------------------------------------------------------------------
// 1) adaptive_avg_pool2d(x, 3): one block per (b,c) plane. 96x96 -> 3x3.
__global__ __launch_bounds__(256) void pool_k(const float* __restrict__ x,
                                              float* __restrict__ pooled) {
    const int bc  = blockIdx.x;
    const int tid = threadIdx.x;
    const int lane = tid & 63, wv = tid >> 6;
    const float4* p4 = (const float4*)(x + (size_t)bc * 9216);
    __shared__ float red[4][9];
#pragma unroll
    for (int bi = 0; bi < 3; ++bi) {
#pragma unroll
        for (int bj = 0; bj < 3; ++bj) {
            int row = bi * 32 + (tid >> 3);
            int c4  = bj * 8 + (tid & 7);
            float4 f = p4[row * 24 + c4];
            float s = f.x + f.y + f.z + f.w;
#pragma unroll
            for (int off = 32; off; off >>= 1) s += __shfl_down(s, off);
            if (lane == 0) red[wv][bi * 3 + bj] = s;
        }
    }
    __syncthreads();
    if (tid < 9) {
        float s = red[0][tid] + red[1][tid] + red[2][tid] + red[3][tid];
        pooled[(size_t)bc * 9 + tid] = s * (1.0f / 1024.0f);
    }
}

// ---------------------------------------------------------------------------
// 2) gen = einsum('bcij,oc->boij', pooled, w_gen) + b_gen
__global__ __launch_bounds__(256) void gen_k(const float* __restrict__ pooled,
                                             const float* __restrict__ wgen,
                                             const float* __restrict__ bgen,
                                             float* __restrict__ gen) {
    __shared__ float pl[256];
    const int b = blockIdx.x / 9, ij = blockIdx.x % 9;
    const int o = threadIdx.x;
    pl[o] = pooled[((size_t)b * 256 + o) * 9 + ij];
    __syncthreads();
    float a = bgen[o];
    const float4* wg4 = (const float4*)(wgen + (size_t)o * 256);
    const float4* pl4 = (const float4*)pl;
#pragma unroll 4
    for (int q = 0; q < 64; ++q) {
        float4 w = wg4[q], p = pl4[q];
        a += w.x * p.x + w.y * p.y + w.z * p.z + w.w * p.w;
    }
    gen[((size_t)b * 256 + o) * 9 + ij] = a;
}

// ---------------------------------------------------------------------------
// 3) weight repack: step-major, granule layout [step][hi][row].
//    wtr granule g (16B = 8 ushorts): g = step*1024 + hi*256 + row,
//    step = ch*9 + tap, content = bf16(w_c1[row][ch*32 + hi*8 + j][tap]).
//    This makes conv A-fragment ds_read_b128 conflict-free (slot = lo&7)
//    while keeping global_load_lds staging lane-linear.
__global__ __launch_bounds__(256) void wtr_k(const float* __restrict__ wc1,
                                             ushort* __restrict__ wtr) {
    int g = blockIdx.x * 256 + threadIdx.x;   // < 73728 granules
    int step = g >> 10;                       // 0..71
    int hi   = (g >> 8) & 3;
    int row  = g & 255;
    int ch = step / 9, tap = step - ch * 9;
    int cbase = ch * 32 + hi * 8;
    ushort tmp[8];
#pragma unroll
    for (int j = 0; j < 8; ++j)
        tmp[j] = f2b(wc1[(size_t)row * 2304 + (size_t)(cbase + j) * 9 + tap]);
    *(uint4*)(wtr + (size_t)g * 8) = *(const uint4*)tmp;
}

// ---------------------------------------------------------------------------
// 4) conv3x3 (C=256->256), implicit GEMM, MFMA 16x16x32 bf16.
//    Block = (b, 2 image rows). M=256 out-ch, N=192 px. 512 thr = 8 waves
//    (4m x 2n): wave = 64 ch x 96 px (one image row), acc[4][6].
//    K-loop: 72 steps (8 c-chunks x 9 taps). A-tile [hi][row] granules,
//    double-buffered via global_load_lds (conflict-free reads). B-halo tile
//    [4 rows][98 px][40 c] staged once per chunk, reused by all 9 taps.
__global__ __launch_bounds__(512) void conv_k(const float* __restrict__ xin,
                                              const ushort* __restrict__ wtr,
                                              const float* __restrict__ bc1,
                                              ushort* __restrict__ yb) {
    __shared__ ushort Al[2][8192];   // [buf][hi 4][row 256][8 c]  16 KB each
    __shared__ ushort Bl[15680];     // [4][98][40]                31360 B

    const int blk = blockIdx.x;
    const int b = blk / 48, hg = blk % 48, h0 = hg * 2;
    const int tid = threadIdx.x;
    const int lane = tid & 63, wv = tid >> 6;
    const int wm = wv & 3, wn = wv >> 2;
    const int lo = lane & 15, hi = lane >> 4;

    // zero px pad columns (px 0 and 97), all 4 rows, c 0..31
    if (tid < 256) {
        int row = tid >> 6, pxp = ((tid >> 5) & 1) ? 97 : 0, c = tid & 31;
        Bl[(row * 98 + pxp) * 40 + c] = 0;
    }

    // ---- A prefetch per-lane source offsets (lane-linear granules)
    const int aoff0 = wv * 1024 + lane * 8;       // granules wv*128 + lane
    const int aoff1 = aoff0 + 512;                // granules +64

    // ---- B staging map: 6 items, id = tid + it*512 -> c fast (bank-free writes)
    const float* gsrc[6];
    int loff[6];
    bool vld[6];
#pragma unroll
    for (int it = 0; it < 6; ++it) {
        int id = tid + it * 512;
        int c = id & 31, rq = id >> 5;            // rq < 96
        int row = rq / 24, q = rq - row * 24;     // row<4, q<24
        int r = h0 + row - 1;
        vld[it] = ((unsigned)r < 96u);
        int rs = vld[it] ? r : 0;
        gsrc[it] = xin + (size_t)b * 2359296 + (size_t)c * 9216 + rs * 96 + q * 4;
        loff[it] = (row * 98 + q * 4 + 1) * 40 + c;
    }

    // ---- A fragment read offsets (ushort idx): hi*2048 + row*8, conflict-free
    int aro[4];
#pragma unroll
    for (int mi = 0; mi < 4; ++mi)
        aro[mi] = hi * 2048 + (wm * 64 + mi * 16 + lo) * 8;

    f32x4 acc[4][6] = {};
    float4 f[6];

    // ---- prologue: issue A(step0), load+write B(chunk0)
    gl_lds16(wtr + aoff0, &Al[0][wv * 1024]);
    gl_lds16(wtr + aoff1, &Al[0][wv * 1024 + 512]);
#pragma unroll
    for (int it = 0; it < 6; ++it) f[it] = *(const float4*)gsrc[it];
#pragma unroll
    for (int it = 0; it < 6; ++it) {
        ushort u0 = 0, u1 = 0, u2 = 0, u3 = 0;
        if (vld[it]) { u0 = f2b(f[it].x); u1 = f2b(f[it].y);
                       u2 = f2b(f[it].z); u3 = f2b(f[it].w); }
        ushort* wp = &Bl[loff[it]];
        wp[0] = u0; wp[40] = u1; wp[80] = u2; wp[120] = u3;
    }
    __syncthreads();   // drains A(0) (vmcnt0) + B writes

    int stp = 0;
    for (int ch = 0; ch < 8; ++ch) {
        // issue next-chunk B loads early; they fly under 9 taps of MFMA
        if (ch < 7) {
#pragma unroll
            for (int it = 0; it < 6; ++it)
                f[it] = *(const float4*)(gsrc[it] + (size_t)(ch + 1) * 294912);
        }
#pragma unroll
        for (int tap = 0; tap < 9; ++tap, ++stp) {
            const int buf = stp & 1;
            if (stp < 71) {   // prefetch A(step+1) into other buffer
                const ushort* as = wtr + (size_t)(stp + 1) * 8192;
                gl_lds16(as + aoff0, &Al[buf ^ 1][wv * 1024]);
                gl_lds16(as + aoff1, &Al[buf ^ 1][wv * 1024 + 512]);
            }
            const int dy = tap / 3, dx = tap % 3;
            bf16x8 af[4], bfr[6];
            const ushort* Ab = &Al[buf][0];
#pragma unroll
            for (int mi = 0; mi < 4; ++mi)
                af[mi] = *(const bf16x8*)(Ab + aro[mi]);
            const ushort* Bp = &Bl[((wn + dy) * 98 + lo + dx) * 40 + hi * 8];
#pragma unroll
            for (int ni = 0; ni < 6; ++ni)
                bfr[ni] = *(const bf16x8*)(Bp + ni * 640);
#pragma unroll
            for (int mi = 0; mi < 4; ++mi)
#pragma unroll
                for (int ni = 0; ni < 6; ++ni)
                    acc[mi][ni] = __builtin_amdgcn_mfma_f32_16x16x32_bf16(
                        af[mi], bfr[ni], acc[mi][ni], 0, 0, 0);
            if (tap == 8) {
                if (ch < 7) {
                    __syncthreads();          // all waves done reading Bl
#pragma unroll
                    for (int it = 0; it < 6; ++it) {
                        ushort u0 = 0, u1 = 0, u2 = 0, u3 = 0;
                        if (vld[it]) { u0 = f2b(f[it].x); u1 = f2b(f[it].y);
                                       u2 = f2b(f[it].z); u3 = f2b(f[it].w); }
                        ushort* wp = &Bl[loff[it]];
                        wp[0] = u0; wp[40] = u1; wp[80] = u2; wp[120] = u3;
                    }
                    __syncthreads();          // B(ch+1) ready + A drained
                }
            } else {
                __syncthreads();              // A(step+1) drained, buffer swap safe
            }
        }
    }

    // epilogue: +bias, store y bf16 NCHW. D: col(px)=lane&15, row=hi*4+rr
    const size_t ybase = (size_t)b * 2359296 + (size_t)(h0 + wn) * 96;
#pragma unroll
    for (int mi = 0; mi < 4; ++mi) {
        const int o0 = wm * 64 + mi * 16 + hi * 4;
#pragma unroll
        for (int rr = 0; rr < 4; ++rr) {
            const int o = o0 + rr;
            const float bias = bc1[o];
#pragma unroll
            for (int ni = 0; ni < 6; ++ni) {
                const int px = ni * 16 + lo;
                yb[ybase + (size_t)o * 9216 + px] = f2b(acc[mi][ni][rr] + bias);
            }
        }
    }
}

// ---------------------------------------------------------------------------
// 5) BN stats: per-(b,c) partial sum/sumsq of y (deterministic, no atomics)
__global__ __launch_bounds__(256) void bnstat_k(const ushort* __restrict__ yb,
                                                float* __restrict__ part) {
    const int bc = blockIdx.x, tid = threadIdx.x;
    const ushort4* p4 = (const ushort4*)(yb + (size_t)bc * 9216);
    float s = 0.f, s2 = 0.f;
#pragma unroll
    for (int it = 0; it < 9; ++it) {
        ushort4 u = p4[tid + it * 256];
        float a = b2f(u.x), bb = b2f(u.y), c = b2f(u.z), d = b2f(u.w);
        s  += a + bb + c + d;
        s2 += a * a + bb * bb + c * c + d * d;
    }
    const int lane = tid & 63, wv = tid >> 6;
#pragma unroll
    for (int off = 32; off; off >>= 1) {
        s += __shfl_down(s, off);
        s2 += __shfl_down(s2, off);
    }
    __shared__ float r1[4], r2[4];
    if (lane == 0) { r1[wv] = s; r2[wv] = s2; }
    __syncthreads();
    if (tid == 0) part[bc]        = r1[0] + r1[1] + r1[2] + r1[3];
    if (tid == 1) part[4096 + bc] = r2[0] + r2[1] + r2[2] + r2[3];
}

// 6) finalize BN: scale/shift per channel
__global__ __launch_bounds__(256) void bnfin_k(const float* __restrict__ part,
                                               const float* __restrict__ gamma,
                                               const float* __restrict__ beta,
                                               float* __restrict__ bnp) {
    const int c = threadIdx.x;
    float s = 0.f, s2 = 0.f;
#pragma unroll
    for (int b = 0; b < 16; ++b) {
        s  += part[b * 256 + c];
        s2 += part[4096 + b * 256 + c];
    }
    const float invN = 1.0f / 147456.0f;
    float mu  = s * invN;
    float var = s2 * invN - mu * mu;
    float sc  = gamma[c] * rsqrtf(var + 1e-5f);
    bnp[c]       = sc;
    bnp[256 + c] = beta[c] - mu * sc;
}

// ---------------------------------------------------------------------------
// 7) depthwise 3x3 with per-(b,c) filters; BN+ReLU applied while staging plane
__global__ __launch_bounds__(256) void dw_k(const ushort* __restrict__ yb,
                                            const float* __restrict__ gen,
                                            const float* __restrict__ bnp,
                                            float* __restrict__ out) {
    __shared__ float pl[9216];
    const int bc = blockIdx.x, tid = threadIdx.x;
    const int c = bc & 255;
    const float sc = bnp[c], sh = bnp[256 + c];
    const ushort4* p4 = (const ushort4*)(yb + (size_t)bc * 9216);
#pragma unroll
    for (int it = 0; it < 9; ++it) {
        int v = tid + it * 256;
        ushort4 u = p4[v];
        float4 f;
        f.x = fmaxf(b2f(u.x) * sc + sh, 0.f);
        f.y = fmaxf(b2f(u.y) * sc + sh, 0.f);
        f.z = fmaxf(b2f(u.z) * sc + sh, 0.f);
        f.w = fmaxf(b2f(u.w) * sc + sh, 0.f);
        *(float4*)&pl[v * 4] = f;
    }
    float g[9];
    const float* gp = gen + (size_t)bc * 9;
#pragma unroll
    for (int k = 0; k < 9; ++k) g[k] = gp[k];
    __syncthreads();
    float* op = out + (size_t)bc * 9216;
#pragma unroll
    for (int it = 0; it < 36; ++it) {
        int i = tid + it * 256;
        int row = i / 96, col = i - row * 96;
        float a = 0.f;
#pragma unroll
        for (int dy = 0; dy < 3; ++dy) {
            int rr = row + dy - 1;
            if (rr < 0 || rr >= 96) continue;
#pragma unroll
            for (int dxq = 0; dxq < 3; ++dxq) {
                int cc = col + dxq - 1;
                if (cc < 0 || cc >= 96) continue;
                a += pl[rr * 96 + cc] * g[dy * 3 + dxq];
            }
        }
        op[i] = a;
    }
}

// ---------------------------------------------------------------------------
extern "C" void kernel_launch(void* const* d_in, const int* in_sizes, int n_in,
                              void* d_out, int out_size, void* d_ws, size_t ws_size,
                              hipStream_t stream) {
    const float* x       = (const float*)d_in[0];
    const float* conv_in = (const float*)d_in[1];
    const float* w_gen   = (const float*)d_in[2];
    const float* b_gen   = (const float*)d_in[3];
    const float* w_c1    = (const float*)d_in[4];
    const float* b_c1    = (const float*)d_in[5];
    const float* gamma   = (const float*)d_in[6];
    const float* beta    = (const float*)d_in[7];
    float* out = (float*)d_out;

    char* ws = (char*)d_ws;
    float*  pooled = (float*)(ws + 0);          // 147456 B
    float*  gen    = (float*)(ws + 147456);     // 147456 B
    ushort* wtr    = (ushort*)(ws + 294912);    // 1179648 B
    float*  part   = (float*)(ws + 1474560);    // 32768 B
    float*  bnp    = (float*)(ws + 1507328);    // 2048 B
    ushort* yb     = (ushort*)(ws + 1509376);   // 75497472 B  (total ~73.4 MB)

    pool_k  <<<4096, 256, 0, stream>>>(x, pooled);
    gen_k   <<<144,  256, 0, stream>>>(pooled, w_gen, b_gen, gen);
    wtr_k   <<<288,  256, 0, stream>>>(w_c1, wtr);
    conv_k  <<<768,  512, 0, stream>>>(conv_in, wtr, b_c1, yb);
    bnstat_k<<<4096, 256, 0, stream>>>(yb, part);
    bnfin_k <<<1,    256, 0, stream>>>(part, gamma, beta, bnp);
    dw_k    <<<4096, 256, 0, stream>>>(yb, gen, bnp, out);
}

// Round 5
// 358.153 us; speedup vs baseline: 1.0695x; 1.0695x over previous
//
#include <hip/hip_runtime.h>

typedef __bf16 bf16x8 __attribute__((ext_vector_type(8)));
typedef float f32x4 __attribute__((ext_vector_type(4)));

static __device__ __forceinline__ ushort f2b(float f) {
    uint32_t x = __float_as_uint(f);
    x += 0x7fffu + ((x >> 16) & 1u);   // RNE (finite values)
    return (ushort)(x >> 16);
}
static __device__ __forceinline__ float b2f(ushort u) {
    return __uint_as_float(((uint32_t)u) << 16);
}

// ---------------------------------------------------------------------------
// 1) adaptive_avg_pool2d(x, 3): one block per (b,c) plane. 96x96 -> 3x3.
__global__ __launch_bounds__(256) void pool_k(const float* __restrict__ x,
                                              float* __restrict__ pooled) {
    const int bc  = blockIdx.x;
    const int tid = threadIdx.x;
    const int lane = tid & 63, wv = tid >> 6;
    const float4* p4 = (const float4*)(x + (size_t)bc * 9216);
    __shared__ float red[4][9];
#pragma unroll
    for (int bi = 0; bi < 3; ++bi) {
#pragma unroll
        for (int bj = 0; bj < 3; ++bj) {
            int row = bi * 32 + (tid >> 3);
            int c4  = bj * 8 + (tid & 7);
            float4 f = p4[row * 24 + c4];
            float s = f.x + f.y + f.z + f.w;
#pragma unroll
            for (int off = 32; off; off >>= 1) s += __shfl_down(s, off);
            if (lane == 0) red[wv][bi * 3 + bj] = s;
        }
    }
    __syncthreads();
    if (tid < 9) {
        float s = red[0][tid] + red[1][tid] + red[2][tid] + red[3][tid];
        pooled[(size_t)bc * 9 + tid] = s * (1.0f / 1024.0f);
    }
}

// ---------------------------------------------------------------------------
// 2) gen = einsum('bcij,oc->boij', pooled, w_gen) + b_gen
__global__ __launch_bounds__(256) void gen_k(const float* __restrict__ pooled,
                                             const float* __restrict__ wgen,
                                             const float* __restrict__ bgen,
                                             float* __restrict__ gen) {
    __shared__ float pl[256];
    const int b = blockIdx.x / 9, ij = blockIdx.x % 9;
    const int o = threadIdx.x;
    pl[o] = pooled[((size_t)b * 256 + o) * 9 + ij];
    __syncthreads();
    float a = bgen[o];
    const float4* wg4 = (const float4*)(wgen + (size_t)o * 256);
    const float4* pl4 = (const float4*)pl;
#pragma unroll 4
    for (int q = 0; q < 64; ++q) {
        float4 w = wg4[q], p = pl4[q];
        a += w.x * p.x + w.y * p.y + w.z * p.z + w.w * p.w;
    }
    gen[((size_t)b * 256 + o) * 9 + ij] = a;
}

// ---------------------------------------------------------------------------
// 3) weight repack: wtr[step][row][c], step = ch*9 + tap, 32 c per step.
//    Granule g (16B = 8 c): g = step*1024 + row*4 + c8,
//    content j = bf16(w_c1[row][ch*32 + c8*8 + j][tap]).
//    A fragment load in conv = one global_load_dwordx4 per (mi).
__global__ __launch_bounds__(256) void wtr_k(const float* __restrict__ wc1,
                                             ushort* __restrict__ wtr) {
    int g = blockIdx.x * 256 + threadIdx.x;   // < 73728 granules
    int step = g >> 10;                       // 0..71
    int row  = (g >> 2) & 255;
    int c8   = g & 3;
    int ch = step / 9, tap = step - ch * 9;
    int cb = ch * 32 + c8 * 8;
    ushort tmp[8];
#pragma unroll
    for (int j = 0; j < 8; ++j)
        tmp[j] = f2b(wc1[(size_t)row * 2304 + (size_t)(cb + j) * 9 + tap]);
    *(uint4*)(wtr + (size_t)g * 8) = *(const uint4*)tmp;
}

// ---------------------------------------------------------------------------
// 4) conv3x3 (C=256->256), implicit GEMM, MFMA 16x16x32 bf16.
//    Block = (b, 2 image rows). M=256 out-ch, N=192 px. 512 thr = 8 waves
//    (4m x 2n). A fragments: global->VGPR ping-pong (L2-resident wtr), no LDS,
//    no per-tap barrier. B-halo [4][98][40] staged per 32-c chunk (2 barriers).
//    Chunk-pair bodies (18 taps) keep ping-pong parity compile-time.
//    Epilogue: y store + per-channel BN partial sums (fused bnstat).
__global__ __launch_bounds__(512) void conv_k(const float* __restrict__ xin,
                                              const ushort* __restrict__ wtr,
                                              const float* __restrict__ bc1,
                                              ushort* __restrict__ yb,
                                              float* __restrict__ part) {
    __shared__ ushort Bl[15680];     // [4 rows][98 px][40 c]  31360 B

    const int blk = blockIdx.x;
    const int b = blk / 48, hg = blk % 48, h0 = hg * 2;
    const int tid = threadIdx.x;
    const int lane = tid & 63, wv = tid >> 6;
    const int wm = wv & 3, wn = wv >> 2;
    const int lo = lane & 15, hi = lane >> 4;

    // zero px pad columns (px 0 and 97), all 4 rows, c 0..31
    if (tid < 256) {
        int row = tid >> 6, pxp = ((tid >> 5) & 1) ? 97 : 0, c = tid & 31;
        Bl[(row * 98 + pxp) * 40 + c] = 0;
    }

    // ---- B staging map: 6 items, id = tid + it*512 -> c fast (bank-free writes)
    const float* gsrc[6];
    int loff[6];
    bool vld[6];
#pragma unroll
    for (int it = 0; it < 6; ++it) {
        int id = tid + it * 512;
        int c = id & 31, rq = id >> 5;            // rq < 96
        int row = rq / 24, q = rq - row * 24;     // row<4, q<24
        int r = h0 + row - 1;
        vld[it] = ((unsigned)r < 96u);
        int rs = vld[it] ? r : 0;
        gsrc[it] = xin + (size_t)b * 2359296 + (size_t)c * 9216 + rs * 96 + q * 4;
        loff[it] = (row * 98 + q * 4 + 1) * 40 + c;
    }

    float4 f[6];
    auto stageB = [&]() {
#pragma unroll
        for (int it = 0; it < 6; ++it) {
            ushort u0 = 0, u1 = 0, u2 = 0, u3 = 0;
            if (vld[it]) { u0 = f2b(f[it].x); u1 = f2b(f[it].y);
                           u2 = f2b(f[it].z); u3 = f2b(f[it].w); }
            ushort* wp = &Bl[loff[it]];
            wp[0] = u0; wp[40] = u1; wp[80] = u2; wp[120] = u3;
        }
    };

    // ---- A fragment granule index (within a step): (row)*4 + hi
    const int agrain = (wm * 64 + lo) * 4 + hi;

    f32x4 acc[4][6] = {};
    uint4 abuf[2][4];

    // ---- prologue: A(step 0) into abuf[0]; stage B(chunk 0)
    {
        const uint4* Ap = (const uint4*)wtr + agrain;
#pragma unroll
        for (int mi = 0; mi < 4; ++mi) abuf[0][mi] = Ap[mi * 64];
    }
#pragma unroll
    for (int it = 0; it < 6; ++it) f[it] = *(const float4*)gsrc[it];
    stageB();
    __syncthreads();

    for (int k = 0; k < 4; ++k) {                 // chunk pair: ch = 2k, 2k+1
        // issue B loads for chunk 2k+1 (consumed at t==8)
#pragma unroll
        for (int it = 0; it < 6; ++it)
            f[it] = *(const float4*)(gsrc[it] + (size_t)(2 * k + 1) * 294912);
#pragma unroll
        for (int t = 0; t < 18; ++t) {            // step = k*18 + t
            const int cur = t & 1;
            // prefetch next step's A fragments into the other buffer
            if (t < 17 || k < 3) {
                const uint4* Ap =
                    (const uint4*)(wtr + (size_t)(k * 18 + t + 1) * 8192) + agrain;
#pragma unroll
                for (int mi = 0; mi < 4; ++mi) abuf[cur ^ 1][mi] = Ap[mi * 64];
            }
            const int tap = (t < 9) ? t : t - 9;
            const int dy = tap / 3, dx = tap % 3;
            bf16x8 bfr[6];
            const ushort* Bp = &Bl[((wn + dy) * 98 + lo + dx) * 40 + hi * 8];
#pragma unroll
            for (int ni = 0; ni < 6; ++ni)
                bfr[ni] = *(const bf16x8*)(Bp + ni * 640);
#pragma unroll
            for (int mi = 0; mi < 4; ++mi) {
                const bf16x8 af = *(const bf16x8*)&abuf[cur][mi];
#pragma unroll
                for (int ni = 0; ni < 6; ++ni)
                    acc[mi][ni] = __builtin_amdgcn_mfma_f32_16x16x32_bf16(
                        af, bfr[ni], acc[mi][ni], 0, 0, 0);
            }
            // B buffer swap points: after taps 8 (mid) and 17 (end, if more)
            if (t == 8) {
                __syncthreads();                  // all waves done reading B(2k)
                stageB();                         // write B(2k+1)
                __syncthreads();
                if (k < 3) {                      // issue B loads for chunk 2k+2
#pragma unroll
                    for (int it = 0; it < 6; ++it)
                        f[it] = *(const float4*)(gsrc[it] + (size_t)(2 * k + 2) * 294912);
                }
            } else if (t == 17 && k < 3) {
                __syncthreads();
                stageB();                         // write B(2k+2)
                __syncthreads();
            }
        }
    }

    // ---- epilogue: +bias, store y bf16; fused BN partial sums
    //      D: col(px)=lane&15, row=hi*4+rr
    const size_t ybase = (size_t)b * 2359296 + (size_t)(h0 + wn) * 96;
#pragma unroll
    for (int mi = 0; mi < 4; ++mi) {
        float s[4], s2[4];
#pragma unroll
        for (int rr = 0; rr < 4; ++rr) {
            const int o = wm * 64 + mi * 16 + hi * 4 + rr;
            const float bias = bc1[o];
            float sv = 0.f, sv2 = 0.f;
#pragma unroll
            for (int ni = 0; ni < 6; ++ni) {
                const int px = ni * 16 + lo;
                float v = acc[mi][ni][rr] + bias;
                yb[ybase + (size_t)o * 9216 + px] = f2b(v);
                sv += v; sv2 += v * v;
            }
            s[rr] = sv; s2[rr] = sv2;
        }
#pragma unroll
        for (int off = 1; off < 16; off <<= 1) {
#pragma unroll
            for (int rr = 0; rr < 4; ++rr) {
                s[rr]  += __shfl_xor(s[rr], off);
                s2[rr] += __shfl_xor(s2[rr], off);
            }
        }
        if (lo == 0) {
#pragma unroll
            for (int rr = 0; rr < 4; ++rr) {
                const int o = wm * 64 + mi * 16 + hi * 4 + rr;
                part[(size_t)o * 1536 + blk * 2 + wn]          = s[rr];
                part[393216 + (size_t)o * 1536 + blk * 2 + wn] = s2[rr];
            }
        }
    }
}

// ---------------------------------------------------------------------------
// 5) BN reduce + finalize: block = channel o; sum 1536 partials (coalesced)
__global__ __launch_bounds__(256) void bnred_k(const float* __restrict__ part,
                                               const float* __restrict__ gamma,
                                               const float* __restrict__ beta,
                                               float* __restrict__ bnp) {
    const int o = blockIdx.x, t = threadIdx.x;
    const float* p0 = part + (size_t)o * 1536;
    const float* p1 = p0 + 393216;
    float s = 0.f, s2 = 0.f;
#pragma unroll
    for (int k = 0; k < 6; ++k) { s += p0[t + k * 256]; s2 += p1[t + k * 256]; }
    const int lane = t & 63, wv = t >> 6;
#pragma unroll
    for (int off = 32; off; off >>= 1) {
        s  += __shfl_down(s, off);
        s2 += __shfl_down(s2, off);
    }
    __shared__ float r1[4], r2[4];
    if (lane == 0) { r1[wv] = s; r2[wv] = s2; }
    __syncthreads();
    if (t == 0) {
        float S  = r1[0] + r1[1] + r1[2] + r1[3];
        float S2 = r2[0] + r2[1] + r2[2] + r2[3];
        const float invN = 1.0f / 147456.0f;
        float mu  = S * invN;
        float var = S2 * invN - mu * mu;
        float sc  = gamma[o] * rsqrtf(var + 1e-5f);
        bnp[o]       = sc;
        bnp[256 + o] = beta[o] - mu * sc;
    }
}

// ---------------------------------------------------------------------------
// 6) depthwise 3x3 with per-(b,c) filters; BN+ReLU applied while staging plane
__global__ __launch_bounds__(256) void dw_k(const ushort* __restrict__ yb,
                                            const float* __restrict__ gen,
                                            const float* __restrict__ bnp,
                                            float* __restrict__ out) {
    __shared__ float pl[9216];
    const int bc = blockIdx.x, tid = threadIdx.x;
    const int c = bc & 255;
    const float sc = bnp[c], sh = bnp[256 + c];
    const ushort4* p4 = (const ushort4*)(yb + (size_t)bc * 9216);
#pragma unroll
    for (int it = 0; it < 9; ++it) {
        int v = tid + it * 256;
        ushort4 u = p4[v];
        float4 f;
        f.x = fmaxf(b2f(u.x) * sc + sh, 0.f);
        f.y = fmaxf(b2f(u.y) * sc + sh, 0.f);
        f.z = fmaxf(b2f(u.z) * sc + sh, 0.f);
        f.w = fmaxf(b2f(u.w) * sc + sh, 0.f);
        *(float4*)&pl[v * 4] = f;
    }
    float g[9];
    const float* gp = gen + (size_t)bc * 9;
#pragma unroll
    for (int k = 0; k < 9; ++k) g[k] = gp[k];
    __syncthreads();
    float* op = out + (size_t)bc * 9216;
#pragma unroll
    for (int it = 0; it < 36; ++it) {
        int i = tid + it * 256;
        int row = i / 96, col = i - row * 96;
        float a = 0.f;
#pragma unroll
        for (int dy = 0; dy < 3; ++dy) {
            int rr = row + dy - 1;
            if (rr < 0 || rr >= 96) continue;
#pragma unroll
            for (int dxq = 0; dxq < 3; ++dxq) {
                int cc = col + dxq - 1;
                if (cc < 0 || cc >= 96) continue;
                a += pl[rr * 96 + cc] * g[dy * 3 + dxq];
            }
        }
        op[i] = a;
    }
}

// ---------------------------------------------------------------------------
extern "C" void kernel_launch(void* const* d_in, const int* in_sizes, int n_in,
                              void* d_out, int out_size, void* d_ws, size_t ws_size,
                              hipStream_t stream) {
    const float* x       = (const float*)d_in[0];
    const float* conv_in = (const float*)d_in[1];
    const float* w_gen   = (const float*)d_in[2];
    const float* b_gen   = (const float*)d_in[3];
    const float* w_c1    = (const float*)d_in[4];
    const float* b_c1    = (const float*)d_in[5];
    const float* gamma   = (const float*)d_in[6];
    const float* beta    = (const float*)d_in[7];
    float* out = (float*)d_out;

    char* ws = (char*)d_ws;
    float*  pooled = (float*)(ws + 0);          // 147456 B
    float*  gen    = (float*)(ws + 147456);     // 147456 B
    ushort* wtr    = (ushort*)(ws + 294912);    // 1179648 B
    float*  part   = (float*)(ws + 1474560);    // 3145728 B (2 x 256 x 1536 f32)
    float*  bnp    = (float*)(ws + 4620288);    // 2048 B
    ushort* yb     = (ushort*)(ws + 4622336);   // 75497472 B (total ~80.1 MB)

    pool_k <<<4096, 256, 0, stream>>>(x, pooled);
    gen_k  <<<144,  256, 0, stream>>>(pooled, w_gen, b_gen, gen);
    wtr_k  <<<288,  256, 0, stream>>>(w_c1, wtr);
    conv_k <<<768,  512, 0, stream>>>(conv_in, wtr, b_c1, yb, part);
    bnred_k<<<256,  256, 0, stream>>>(part, gamma, beta, bnp);
    dw_k   <<<4096, 256, 0, stream>>>(yb, gen, bnp, out);
}